// Round 7
// baseline (269.386 us; speedup 1.0000x reference)
//
#include <hip/hip_runtime.h>
#include <hip/hip_bf16.h>

// ---------------------------------------------------------------------------
// TernaryDense: C[M,N] = A[M,K] (fp32) @ ternary(W[K,N]) (fp32)
// Round 7: persistent 2-tile blocks (grid=256). Each block does two
// N-adjacent 256^2 tiles; the r6 single-barrier 8-phase pipeline rolls
// across the tile boundary (wrap stages redirected to tile1's B columns),
// and tile0's epilogue is interleaved into tile1's first 4 phases.
// Nontemporal C stores. K-loop schedule identical to r6 (proven).
// ---------------------------------------------------------------------------

#define LDSP(p) ((__attribute__((address_space(3))) void*)(p))
#define GLBP(p) ((const __attribute__((address_space(1))) void*)(p))

typedef __attribute__((ext_vector_type(8))) short bf16x8;
typedef __attribute__((ext_vector_type(4))) float f32x4;

static __device__ __forceinline__ unsigned short f2bf_rne(float f) {
    unsigned u = __float_as_uint(f);
    unsigned r = (u + 0x7FFFu + ((u >> 16) & 1u)) >> 16;
    return (unsigned short)r;
}

static __device__ __forceinline__ unsigned short tern_bf16(float v) {
    float a = fabsf(v);
    if (a >= 0.5f && a < 1.5f)
        return (v > 0.0f) ? (unsigned short)0x3F80u : (unsigned short)0xBF80u;
    return (unsigned short)0;
}

// --- pre-pass 1: A fp32 -> bf16 ---------------------------------------------
__global__ __launch_bounds__(256) void cvtA_kernel(
    const float* __restrict__ in, unsigned short* __restrict__ out, long n8) {
    long i = (long)blockIdx.x * blockDim.x + threadIdx.x;
    long stride = (long)gridDim.x * blockDim.x;
    for (; i < n8; i += stride) {
        float4 v0 = *(const float4*)(in + i * 8);
        float4 v1 = *(const float4*)(in + i * 8 + 4);
        unsigned short o[8] = {f2bf_rne(v0.x), f2bf_rne(v0.y), f2bf_rne(v0.z), f2bf_rne(v0.w),
                               f2bf_rne(v1.x), f2bf_rne(v1.y), f2bf_rne(v1.z), f2bf_rne(v1.w)};
        *(int4*)(out + i * 8) = *(const int4*)o;
    }
}

// --- pre-pass 2: ternarize W[K,N] and transpose -> Wt[N,K] bf16 -------------
__global__ __launch_bounds__(256) void ternT_kernel(
    const float* __restrict__ W, unsigned short* __restrict__ Wt, int K, int N) {
    __shared__ unsigned short tile[64][72];
    const int k0 = blockIdx.y * 64;
    const int n0 = blockIdx.x * 64;
    const int t = threadIdx.x;
#pragma unroll
    for (int i = 0; i < 4; ++i) {
        int e = i * 1024 + t * 4;
        int r = e >> 6, c = e & 63;
        float4 v = *(const float4*)(W + (size_t)(k0 + r) * N + n0 + c);
        tile[r][c + 0] = tern_bf16(v.x);
        tile[r][c + 1] = tern_bf16(v.y);
        tile[r][c + 2] = tern_bf16(v.z);
        tile[r][c + 3] = tern_bf16(v.w);
    }
    __syncthreads();
#pragma unroll
    for (int i = 0; i < 2; ++i) {
        int e = i * 2048 + t * 8;
        int n = e >> 6, kk = e & 63;
        unsigned short o[8];
#pragma unroll
        for (int j = 0; j < 8; ++j) o[j] = tile[kk + j][n];
        *(int4*)(Wt + (size_t)(n0 + n) * K + k0 + kk) = *(const int4*)o;
    }
}

// --- persistent single-barrier 8-phase 256^2 GEMM, 16x16x32 MFMA ------------
#define BM 256
#define BN 256
#define BK 64

#define FENCE() asm volatile("" ::: "memory")
#define BAR()                          \
    do {                               \
        FENCE();                       \
        __builtin_amdgcn_s_barrier();  \
        FENCE();                       \
    } while (0)

template <int N, int K>
__global__ __launch_bounds__(512, 2) void gemmp_kernel(
    const unsigned short* __restrict__ A,   // M x K bf16
    const unsigned short* __restrict__ Bt,  // N x K bf16
    float* __restrict__ C, int M) {
    __shared__ alignas(16) unsigned short lds[2][2][BM * BK];  // 128 KB

    const int t = threadIdx.x;
    const int lane = t & 63;
    const int wave = t >> 6;
    const int wm = wave >> 2;   // 0..1  -> 128 rows
    const int wn = wave & 3;    // 0..3  -> 64 cols
    const int l15 = lane & 15;
    const int kgrp = lane >> 4; // 0..3

    // T1: bijective XCD swizzle over 256 persistent blocks
    const int qq = 256 >> 3;   // 32
    const int swz = ((int)blockIdx.x & 7) * qq + ((int)blockIdx.x >> 3);
    const int brow = (swz >> 3) * BM;      // 32 M-row groups
    const int bcb = swz & 7;               // 8 column bases
    const int bcol0 = bcb * BN;            // tile0 columns
    const int bcol1 = (bcb + 8) * BN;      // tile1 columns (same A panel)

    constexpr int NKT = K / BK;   // 64
    constexpr int NIT = NKT / 2;  // 32

    // stage one 16KB half (mat 0=A,1=B; h 0/1) of K-tile kt into buffer b.
    // LDS dest linear; inverse T2 swizzle applied to the GLOBAL source addr.
    auto stage_half = [&](int b, int mat, int h, int kt, int rowbase) {
        const unsigned short* sb = mat ? Bt : A;
#pragma unroll
        for (int iss = 0; iss < 2; ++iss) {
            int Lb = h * 16384 + iss * 8192 + t * 16;  // byte in 32KB tile
            int row = Lb >> 7;                          // tile row 0..255
            int kb = (Lb & 127) ^ ((row & 7) << 4);     // swizzled k-byte
            const char* src = (const char*)sb +
                ((size_t)(rowbase + row) * K + (size_t)kt * BK) * 2 + kb;
            unsigned short* dst =
                &lds[b][mat][0] + (h * 16384 + iss * 8192 + wave * 1024) / 2;
            __builtin_amdgcn_global_load_lds(GLBP(src), LDSP(dst), 16, 0, 0);
        }
    };

    auto read_A = [&](int b, int mf, int ks) -> bf16x8 {
        int row = wm * 128 + mf * 16 + l15;
        int kb = (kgrp * 16 + ks * 64) ^ ((row & 7) << 4);
        return *(const bf16x8*)((const char*)&lds[b][0][0] + row * 128 + kb);
    };
    auto read_B = [&](int b, int nf, int ks) -> bf16x8 {
        int row = wn * 64 + nf * 16 + l15;
        int kb = (kgrp * 16 + ks * 64) ^ ((row & 7) << 4);
        return *(const bf16x8*)((const char*)&lds[b][1][0] + row * 128 + kb);
    };

    f32x4 acc[8][4] = {};
    bf16x8 af[4][2], bfr01[2][2], bfr23[2][2];

    const int scrow = brow + wm * 128;     // store coords (rows, both tiles)
    const int sccol0 = bcol0 + wn * 64;    // tile0 store cols
    const int sccol1 = bcol1 + wn * 64;    // tile1 store cols

    // 16 MFMA = one C-quadrant (4 mf x 2 nf x 2 ks)
#define QMFMA(BF, MB, NB)                                                      \
    do {                                                                       \
        __builtin_amdgcn_s_setprio(1);                                         \
        _Pragma("unroll") for (int ks = 0; ks < 2; ++ks)                       \
            _Pragma("unroll") for (int mf = 0; mf < 4; ++mf)                   \
                _Pragma("unroll") for (int nf = 0; nf < 2; ++nf)               \
                    acc[(MB) + mf][(NB) + nf] =                                \
                        __builtin_amdgcn_mfma_f32_16x16x32_bf16(               \
                            af[mf][ks], BF[nf][ks], acc[(MB) + mf][(NB) + nf], \
                            0, 0, 0);                                          \
        __builtin_amdgcn_s_setprio(0);                                         \
    } while (0)

    // store one tile0 quadrant (nontemporal) then zero it for tile1
#define STORE_Q(MB, NB)                                                        \
    do {                                                                       \
        _Pragma("unroll") for (int mf = 0; mf < 4; ++mf)                       \
            _Pragma("unroll") for (int nf = 0; nf < 2; ++nf)                   \
                _Pragma("unroll") for (int r = 0; r < 4; ++r) {                \
                    int row = scrow + ((MB) + mf) * 16 + kgrp * 4 + r;         \
                    int col = sccol0 + ((NB) + nf) * 16 + l15;                 \
                    __builtin_nontemporal_store(                               \
                        acc[(MB) + mf][(NB) + nf][r],                          \
                        &C[(size_t)row * N + col]);                           \
                }                                                              \
        _Pragma("unroll") for (int mf = 0; mf < 4; ++mf)                       \
            _Pragma("unroll") for (int nf = 0; nf < 2; ++nf)                   \
                acc[(MB) + mf][(NB) + nf] = (f32x4){0.f, 0.f, 0.f, 0.f};       \
    } while (0)

    // one pipeline iteration = 2 K-tiles, 8 phases, single barrier per phase.
    // kA_: buf1.A fill (consumed this iter); kB0_/kB1_: next K-tiles;
    // bcB_: column base for B stages (redirected at tile boundary);
    // ST_: interleave tile0 quadrant stores (tile1's first iter only).
#define KITER(kA_, kB0_, kB1_, bcB_, ST_)                                      \
    {                                                                          \
        /* ph1: reads af(buf0 m0-3)+bfr01(buf0); stage buf1.A.h0 */            \
        _Pragma("unroll") for (int ks = 0; ks < 2; ++ks) {                     \
            _Pragma("unroll") for (int mf = 0; mf < 4; ++mf)                   \
                af[mf][ks] = read_A(0, mf, ks);                                \
            _Pragma("unroll") for (int nf = 0; nf < 2; ++nf)                   \
                bfr01[nf][ks] = read_B(0, nf, ks);                             \
        }                                                                      \
        stage_half(1, 0, 0, (kA_), brow);                                      \
        if (ST_) { STORE_Q(0, 0); }                                            \
        BAR();                                                                 \
        QMFMA(bfr01, 0, 0);                                                    \
        /* ph2: reads bfr23(buf0); stage buf1.A.h1 */                          \
        _Pragma("unroll") for (int ks = 0; ks < 2; ++ks)                       \
            _Pragma("unroll") for (int nf = 0; nf < 2; ++nf)                   \
                bfr23[nf][ks] = read_B(0, nf + 2, ks);                         \
        stage_half(1, 0, 1, (kA_), brow);                                      \
        if (ST_) { STORE_Q(0, 2); }                                            \
        BAR();                                                                 \
        QMFMA(bfr23, 0, 2);                                                    \
        /* ph3: reads af(buf0 m4-7); stage buf0.B.h0(kB0_) */                  \
        _Pragma("unroll") for (int ks = 0; ks < 2; ++ks)                       \
            _Pragma("unroll") for (int mf = 0; mf < 4; ++mf)                   \
                af[mf][ks] = read_A(0, mf + 4, ks);                            \
        stage_half(0, 1, 0, (kB0_), (bcB_));                                   \
        if (ST_) { STORE_Q(4, 0); }                                            \
        BAR();                                                                 \
        QMFMA(bfr01, 4, 0);                                                    \
        /* ph4: stage buf0.B.h1(kB0_); vmcnt(4) retires buf1(kA_) */           \
        stage_half(0, 1, 1, (kB0_), (bcB_));                                   \
        if (ST_) { STORE_Q(4, 2); }                                            \
        asm volatile("s_waitcnt vmcnt(4)" ::: "memory");                       \
        BAR();                                                                 \
        QMFMA(bfr23, 4, 2);                                                    \
        /* ph5: reads af(buf1 m0-3)+bfr01(buf1); stage buf0.A.h0(kB0_) */      \
        _Pragma("unroll") for (int ks = 0; ks < 2; ++ks) {                     \
            _Pragma("unroll") for (int mf = 0; mf < 4; ++mf)                   \
                af[mf][ks] = read_A(1, mf, ks);                                \
            _Pragma("unroll") for (int nf = 0; nf < 2; ++nf)                   \
                bfr01[nf][ks] = read_B(1, nf, ks);                             \
        }                                                                      \
        stage_half(0, 0, 0, (kB0_), brow);                                     \
        BAR();                                                                 \
        QMFMA(bfr01, 0, 0);                                                    \
        /* ph6: reads bfr23(buf1); stage buf0.A.h1(kB0_) */                    \
        _Pragma("unroll") for (int ks = 0; ks < 2; ++ks)                       \
            _Pragma("unroll") for (int nf = 0; nf < 2; ++nf)                   \
                bfr23[nf][ks] = read_B(1, nf + 2, ks);                         \
        stage_half(0, 0, 1, (kB0_), brow);                                     \
        BAR();                                                                 \
        QMFMA(bfr23, 0, 2);                                                    \
        /* ph7: reads af(buf1 m4-7); stage buf1.B.h0(kB1_) */                  \
        _Pragma("unroll") for (int ks = 0; ks < 2; ++ks)                       \
            _Pragma("unroll") for (int mf = 0; mf < 4; ++mf)                   \
                af[mf][ks] = read_A(1, mf + 4, ks);                            \
        stage_half(1, 1, 0, (kB1_), (bcB_));                                   \
        BAR();                                                                 \
        QMFMA(bfr01, 4, 0);                                                    \
        /* ph8: stage buf1.B.h1(kB1_); vmcnt(4) retires buf0(kB0_) */          \
        stage_half(1, 1, 1, (kB1_), (bcB_));                                   \
        asm volatile("s_waitcnt vmcnt(4)" ::: "memory");                       \
        BAR();                                                                 \
        QMFMA(bfr23, 4, 2);                                                    \
    }

    // ---- prologue (tile0): buf0 fully (kt0), buf1.B (kt1)
    stage_half(0, 1, 0, 0, bcol0);
    stage_half(0, 1, 1, 0, bcol0);
    stage_half(0, 0, 0, 0, brow);
    stage_half(0, 0, 1, 0, brow);
    stage_half(1, 1, 0, 1, bcol0);
    stage_half(1, 1, 1, 1, bcol0);
    asm volatile("s_waitcnt vmcnt(4)" ::: "memory");
    BAR();

    // ---- tile0 K-loop; last iter's wrap stages fill tile1's kt0/kt1
    for (int it = 0; it < NIT - 1; ++it)
        KITER(2 * it + 1, 2 * it + 2, 2 * it + 3, bcol0, 0)
    KITER(2 * (NIT - 1) + 1, 0, 1, bcol1, 0)

    // ---- tile1 K-loop; first iter interleaves tile0's epilogue stores
    KITER(1, 2, 3, bcol1, 1)
    for (int it = 1; it < NIT - 1; ++it)
        KITER(2 * it + 1, 2 * it + 2, 2 * it + 3, bcol1, 0)
    KITER(2 * (NIT - 1) + 1, 0, 1, bcol1, 0)   // wrap stages harmless

#undef KITER
#undef STORE_Q
#undef QMFMA

    // ---- final epilogue: tile1 (nontemporal)
#pragma unroll
    for (int mf = 0; mf < 8; ++mf)
#pragma unroll
        for (int nf = 0; nf < 4; ++nf)
#pragma unroll
            for (int r = 0; r < 4; ++r) {
                int row = scrow + mf * 16 + kgrp * 4 + r;
                int col = sccol1 + nf * 16 + l15;
                __builtin_nontemporal_store(acc[mf][nf][r],
                                            &C[(size_t)row * N + col]);
            }
}

// --- fallback: naive fp32 (never expected to trigger) -----------------------
__global__ void naive_kernel(const float* __restrict__ A, const float* __restrict__ W,
                             float* __restrict__ C, int M, int N, int K) {
    int col = blockIdx.x * blockDim.x + threadIdx.x;
    int row = blockIdx.y;
    if (col >= N || row >= M) return;
    float s = 0.0f;
    for (int k = 0; k < K; ++k) {
        float w = W[(size_t)k * N + col];
        float a = fabsf(w);
        if (a >= 0.5f && a < 1.5f) s += (w > 0.0f) ? A[(size_t)row * K + k] : -A[(size_t)row * K + k];
    }
    C[(size_t)row * N + col] = s;
}

extern "C" void kernel_launch(void* const* d_in, const int* in_sizes, int n_in,
                              void* d_out, int out_size, void* d_ws, size_t ws_size,
                              hipStream_t stream) {
    const float* A = (const float*)d_in[0];  // [M,K]
    const float* W = (const float*)d_in[1];  // [K,N]
    float* C = (float*)d_out;

    constexpr int K = 4096, N = 4096;
    const int M = in_sizes[0] / K;  // 8192

    const size_t needA = (size_t)M * K * 2;
    const size_t needW = (size_t)N * K * 2;
    // persistent geometry assumes 32 brow-groups x 16 bcol tiles (M=8192)
    const bool ok = (M == 8192) && (ws_size >= needA + needW);
    if (!ok) {
        dim3 grid((N + 255) / 256, M);
        naive_kernel<<<grid, 256, 0, stream>>>(A, W, C, M, N, K);
        return;
    }

    unsigned short* Abf = (unsigned short*)d_ws;
    unsigned short* Wt = (unsigned short*)((char*)d_ws + needA);

    cvtA_kernel<<<2048, 256, 0, stream>>>(A, Abf, (long)M * K / 8);
    ternT_kernel<<<dim3(N / 64, K / 64), 256, 0, stream>>>(W, Wt, K, N);

    gemmp_kernel<N, K><<<dim3(256), 512, 0, stream>>>(Abf, Wt, C, M);
}